// Round 6
// baseline (295.595 us; speedup 1.0000x reference)
//
#include <hip/hip_runtime.h>
#include <hip/hip_bf16.h>

#define kB 16
#define kS 2048
#define kD 1024
#define kH 128
#define kBS (kB * kS)

typedef short s8v __attribute__((ext_vector_type(8)));
typedef float f4v __attribute__((ext_vector_type(4)));
typedef float f16v __attribute__((ext_vector_type(16)));
typedef unsigned short us4 __attribute__((ext_vector_type(4)));
typedef unsigned short us8 __attribute__((ext_vector_type(8)));

__device__ __forceinline__ unsigned short f2bf(float f) {
    __hip_bfloat16 h = __float2bfloat16(f);
    return __builtin_bit_cast(unsigned short, h);
}

// async global->LDS DMA, 16B per lane, LDS dest = wave-uniform base + lane*16
__device__ __forceinline__ void gl16(const void* g, void* l) {
    __builtin_amdgcn_global_load_lds(
        (const __attribute__((address_space(1))) unsigned int*)g,
        (__attribute__((address_space(3))) unsigned int*)l, 16, 0, 0);
}

// ---------------------------------------------------------------------------
// Kernel 0: W[1024][128] fp32 -> Wt[384][1024] bf16 (transposed, q|k|v).
// Wq pre-scaled by H^-0.5.  (unchanged)
// ---------------------------------------------------------------------------
__global__ void prep_w(const float* __restrict__ Wq, const float* __restrict__ Wk,
                       const float* __restrict__ Wv, unsigned short* __restrict__ Wt)
{
    const int g = blockIdx.x;
    const float* W = (g == 0) ? Wq : (g == 1) ? Wk : Wv;
    const float sc = (g == 0) ? 0.08838834764831845f : 1.0f;  // 128^-0.5 folded into Wq
    unsigned short* o = Wt + (size_t)g * 128 * 1024;
    const int t = threadIdx.x;
    const int n = t & 127;
    const int half = t >> 7;
    const int kbase = blockIdx.y * 64 + half * 32;
    #pragma unroll
    for (int c = 0; c < 4; ++c) {
        int kb = kbase + c * 8;
        us8 v;
        #pragma unroll
        for (int j = 0; j < 8; ++j) v[j] = f2bf(W[(size_t)(kb + j) * kH + n] * sc);
        *(us8*)(o + (size_t)n * 1024 + kb) = v;
    }
}

// ---------------------------------------------------------------------------
// Kernel 1 (R9, unchanged): fused QKV GEMM, m97-shape. BM=128 x BN=384,
// BK=64, 16 steps. 8 waves (2m x 4n), acc[4][6]. 256 blocks = 1/CU.
// B via global_load_lds with both-sides XOR chunk swizzle; A reg-staged.
// ---------------------------------------------------------------------------
#define AOFF(b_) ((b_) * 8704)
#define BOFF(b_) (17408 + (b_) * 24576)

#define STAGE(b_, tt_) do {                                                   \
    _Pragma("unroll")                                                         \
    for (int u = 0; u < 4; ++u)                                               \
        xa[u] = *(const float4*)(Xp + (tt_) * 64 + u * 4);                    \
    _Pragma("unroll")                                                         \
    for (int ci = 0; ci < 6; ++ci) {                                          \
        const int rb = w * 48 + ci * 8;                                       \
        gl16(WpL + (size_t)rb * 1024 + (tt_) * 64, &smem[BOFF(b_) + rb * 64]);\
    }                                                                         \
} while (0)

#define AWRITE(b_) do {                                                       \
    _Pragma("unroll")                                                         \
    for (int u2 = 0; u2 < 2; ++u2) {                                          \
        us8 aw;                                                               \
        aw[0] = f2bf(xa[2*u2].x);   aw[1] = f2bf(xa[2*u2].y);                 \
        aw[2] = f2bf(xa[2*u2].z);   aw[3] = f2bf(xa[2*u2].w);                 \
        aw[4] = f2bf(xa[2*u2+1].x); aw[5] = f2bf(xa[2*u2+1].y);               \
        aw[6] = f2bf(xa[2*u2+1].z); aw[7] = f2bf(xa[2*u2+1].w);               \
        *(us8*)&smem[AOFF(b_) + arow * 68 + ac16 + u2 * 8] = aw;              \
    }                                                                         \
} while (0)

__global__ __launch_bounds__(512, 2) void qkv_gemm(
    const float* __restrict__ X, const unsigned short* __restrict__ Wt,
    unsigned short* __restrict__ ws)
{
    __shared__ __align__(16) unsigned short smem[66560];   // 133 KB

    const int t    = threadIdx.x;
    const int L    = t & 63;
    const int w    = t >> 6;                 // wave 0..7
    const int wr   = w >> 2;                 // m-half 0..1
    const int wc   = w & 3;                  // n-quarter 0..3
    const int col  = L & 15;
    const int quad = L >> 4;
    const int m0   = blockIdx.x * 128;

    f4v acc[4][6];
    #pragma unroll
    for (int i = 0; i < 4; ++i)
        #pragma unroll
        for (int j = 0; j < 6; ++j) { f4v z = {0.f, 0.f, 0.f, 0.f}; acc[i][j] = z; }

    const int arow = t >> 2;                 // 0..127
    const int ac16 = (t & 3) * 16;           // k-base 0,16,32,48
    const float* Xp = X + (size_t)(m0 + arow) * kD + ac16;
    // B DMA source, pre-swizzled: lane L covers row rb+(L>>3), LDS chunk (L&7)
    // holds global chunk (L&7)^(L>>3)
    const unsigned short* WpL = Wt + (size_t)(L >> 3) * 1024
                                + (((L & 7) ^ (L >> 3)) * 8);

    float4 xa[4];

    STAGE(0, 0);
    AWRITE(0);
    __syncthreads();     // drains tile-0 DMAs

    #pragma unroll 2
    for (int tt = 0; tt < 16; ++tt) {
        const int cb = tt & 1;
        if (tt < 15) STAGE(cb ^ 1, tt + 1);     // fire-and-forget next tile
        const int ab = AOFF(cb), bbs = BOFF(cb);
        #pragma unroll
        for (int ks = 0; ks < 2; ++ks) {
            s8v Af[4], Bf[6];
            #pragma unroll
            for (int i = 0; i < 4; ++i)
                Af[i] = *(const s8v*)&smem[ab + (wr * 64 + i * 16 + col) * 68
                                           + ks * 32 + quad * 8];
            const int swz = (((ks * 4 + quad) ^ (col & 7)) * 8);
            #pragma unroll
            for (int j = 0; j < 6; ++j) {
                const int n = wc * 96 + j * 16 + col;
                Bf[j] = *(const s8v*)&smem[bbs + n * 64 + swz];
            }
            #pragma unroll
            for (int i = 0; i < 4; ++i)
                #pragma unroll
                for (int j = 0; j < 6; ++j)
                    acc[i][j] = __builtin_amdgcn_mfma_f32_16x16x32_bf16(
                        Af[i], Bf[j], acc[i][j], 0, 0, 0);
        }
        if (tt < 15) AWRITE(cb ^ 1);
        __syncthreads();
    }

    // ---- epilogue: repack via LDS, write q/k [s][h] and v^T [b][h][s] ----
    for (int g = 0; g < 3; ++g) {
        __syncthreads();
        #pragma unroll
        for (int j = 0; j < 6; ++j) {
            if (((96 * wc + 16 * j) >> 7) != g) continue;   // wave-uniform
            int n = 96 * wc + 16 * j + col;
            if (g < 2) {
                int ng = n - g * 128;
                #pragma unroll
                for (int i = 0; i < 4; ++i)
                    #pragma unroll
                    for (int rg = 0; rg < 4; ++rg)
                        smem[(wr * 64 + i * 16 + quad * 4 + rg) * 136 + ng] =
                            f2bf(acc[i][j][rg]);
            } else {
                int h = n - 256;
                #pragma unroll
                for (int i = 0; i < 4; ++i) {
                    us4 pk = { f2bf(acc[i][j][0]), f2bf(acc[i][j][1]),
                               f2bf(acc[i][j][2]), f2bf(acc[i][j][3]) };
                    *(us4*)&smem[h * 136 + wr * 64 + i * 16 + quad * 4] = pk;
                }
            }
        }
        __syncthreads();
        if (g < 2) {
            unsigned short* outp = ws + (size_t)g * kBS * kH;
            int row = t >> 2, hc = (t & 3) * 32;
            #pragma unroll
            for (int u = 0; u < 4; ++u) {
                us8 v = *(const us8*)&smem[row * 136 + hc + u * 8];
                *(us8*)(outp + (size_t)(m0 + row) * kH + hc + u * 8) = v;
            }
        } else {
            unsigned short* vtp = ws + (size_t)2 * kBS * kH;
            int h = t >> 2, sc2 = (t & 3) * 32;
            int bb = m0 >> 11, sl = m0 & 2047;
            #pragma unroll
            for (int u = 0; u < 4; ++u) {
                us8 v = *(const us8*)&smem[h * 136 + sc2 + u * 8];
                *(us8*)(vtp + ((size_t)bb * kH + h) * kS + sl + sc2 + u * 8) = v;
            }
        }
    }
}

// ---------------------------------------------------------------------------
// Kernel 2 (R10): causal attention — 4-wave SPLIT-K per q-slot with PROPER
// VGPR budget: __launch_bounds__(256,2) -> 256-VGPR cap (R8's failure was
// the (256,4) 128/64-VGPR clamp -> 331 MB scratch). 1024 blocks x 4 waves
// = 4 waves/SIMD. XCD-aware 1D grid: each XCD owns 2 batches -> K+V (2 MB)
// L2-resident. Heavy q-slots dispatched first within each XCD.
// ---------------------------------------------------------------------------
__global__ __launch_bounds__(256, 2) void attn(
    const unsigned short* __restrict__ ws, float* __restrict__ out)
{
    __shared__ float Ob[4096];               // 16 KB combine chunk
    __shared__ float Lsums[128];
    __shared__ unsigned short Ps[4 * 1152];  // per-wave P[32][36]

    const int t   = threadIdx.x;
    const int w   = t >> 6;                  // wave 0..3
    const int L   = t & 63;
    const int l5  = L >> 5;
    const int c32 = L & 31;

    // XCD-aware decode: flat = blockIdx.x (0..1023); XCD = flat&7 (round
    // robin); each XCD gets k=flat>>3 in 0..127 -> 2 batches x 64 slots.
    const int flat = blockIdx.x;
    const int xcd  = flat & 7;
    const int kk   = flat >> 3;
    const int b    = xcd * 2 + (kk >> 6);
    const int ii2  = kk & 63;
    const int g2 = ii2 >> 4, ii = ii2 & 15;
    const int s  = (g2 == 0) ? 63 - ii : (g2 == 1) ? 32 + ii
                 : (g2 == 2) ? 31 - ii : ii;           // bijective onto 0..63

    const unsigned short* qp = ws;
    const unsigned short* kp = ws + (size_t)kBS * kH + (size_t)b * kS * kH;
    const unsigned short* vt = ws + (size_t)2 * kBS * kH + (size_t)b * kH * kS;

    const size_t qrow = (size_t)b * kS + s * 32 + c32;
    unsigned short* myPs = Ps + w * 1152;

    // Q B-frags (n=lane&31 -> q=c32, k=l5*8+j at k-offset ks*16)
    s8v Qf[8];
    #pragma unroll
    for (int ks = 0; ks < 8; ++ks)
        Qf[ks] = *(const s8v*)(qp + qrow * kH + ks * 16 + l5 * 8);

    f16v O[4];
    #pragma unroll
    for (int nt = 0; nt < 4; ++nt)
        #pragma unroll
        for (int r = 0; r < 16; ++r) O[nt][r] = 0.f;
    float lsum = 0.f;

    // prefetch first K tile of this wave (rows w*32+c32 always in-bounds)
    s8v Kf[8];
    #pragma unroll
    for (int ks = 0; ks < 8; ++ks)
        Kf[ks] = *(const s8v*)(kp + (size_t)(w * 32 + c32) * kH + ks * 16 + l5 * 8);

    for (int T = w; T <= s; T += 4) {
        const int kb = T * 32;
        // V^T A-frags (m = h within 32-group = c32, k = key)
        s8v Vf[2][4];
        #pragma unroll
        for (int k2 = 0; k2 < 2; ++k2)
            #pragma unroll
            for (int nt = 0; nt < 4; ++nt)
                Vf[k2][nt] = *(const s8v*)(vt + (size_t)(nt * 32 + c32) * kS
                                           + kb + k2 * 16 + l5 * 8);
        // S^T = K Q^T
        f16v Sv;
        #pragma unroll
        for (int r = 0; r < 16; ++r) Sv[r] = 0.f;
        #pragma unroll
        for (int ks = 0; ks < 8; ++ks)
            Sv = __builtin_amdgcn_mfma_f32_32x32x16_bf16(Kf[ks], Qf[ks], Sv, 0, 0, 0);
        // prefetch this wave's next K tile (stride 4 tiles = +128 rows)
        if (T + 4 <= s) {
            #pragma unroll
            for (int ks = 0; ks < 8; ++ks)
                Kf[ks] = *(const s8v*)(kp + (size_t)(kb + 128 + c32) * kH + ks * 16 + l5 * 8);
        }
        // mask (diagonal tile) + exp + P store; lane holds 16 keys of q=c32
        const bool dm = (T == s);
        #pragma unroll
        for (int g4 = 0; g4 < 4; ++g4) {
            us4 pk;
            #pragma unroll
            for (int u = 0; u < 4; ++u) {
                int krow = u + 8 * g4 + 4 * l5;       // C-layout row = key
                float v = Sv[g4 * 4 + u];
                if (dm && krow > c32) v = -__builtin_inff();
                float e = __expf(v);
                lsum += e;
                pk[u] = f2bf(e);
            }
            *(us4*)&myPs[c32 * 36 + 8 * g4 + 4 * l5] = pk;
        }
        // O^T += V^T P^T (same-wave LDS roundtrip)
        #pragma unroll
        for (int k2 = 0; k2 < 2; ++k2) {
            us4 plo = *(const us4*)&myPs[c32 * 36 + k2 * 16 + l5 * 8];
            us4 phi = *(const us4*)&myPs[c32 * 36 + k2 * 16 + l5 * 8 + 4];
            us8 pc;
            pc[0]=plo[0]; pc[1]=plo[1]; pc[2]=plo[2]; pc[3]=plo[3];
            pc[4]=phi[0]; pc[5]=phi[1]; pc[6]=phi[2]; pc[7]=phi[3];
            s8v Pb = __builtin_bit_cast(s8v, pc);
            #pragma unroll
            for (int nt = 0; nt < 4; ++nt)
                O[nt] = __builtin_amdgcn_mfma_f32_32x32x16_bf16(Vf[k2][nt], Pb, O[nt], 0, 0, 0);
        }
    }

    // ---- combine partial l across waves ----
    float lw = lsum + __shfl_xor(lsum, 32);      // per-lane q=c32, this wave
    if (l5 == 0) Lsums[w * 32 + c32] = lw;
    __syncthreads();
    const float inv = 1.0f / (Lsums[c32] + Lsums[32 + c32] +
                              Lsums[64 + c32] + Lsums[96 + c32]);

    // ---- combine partial O across waves, chunked by nt (16 KB buffer) ----
    #pragma unroll
    for (int nt = 0; nt < 4; ++nt) {
        #pragma unroll
        for (int g4 = 0; g4 < 4; ++g4) {
            f4v v = { O[nt][g4 * 4 + 0], O[nt][g4 * 4 + 1],
                      O[nt][g4 * 4 + 2], O[nt][g4 * 4 + 3] };
            *(f4v*)&Ob[((w * 4 + g4) * 64 + L) * 4] = v;     // contiguous/wave
        }
        __syncthreads();
        if (w == nt) {
            #pragma unroll
            for (int g4 = 0; g4 < 4; ++g4) {
                f4v a0 = *(const f4v*)&Ob[((0 * 4 + g4) * 64 + L) * 4];
                f4v a1 = *(const f4v*)&Ob[((1 * 4 + g4) * 64 + L) * 4];
                f4v a2 = *(const f4v*)&Ob[((2 * 4 + g4) * 64 + L) * 4];
                f4v a3 = *(const f4v*)&Ob[((3 * 4 + g4) * 64 + L) * 4];
                f4v r = (a0 + a1) + (a2 + a3);
                r[0] *= inv; r[1] *= inv; r[2] *= inv; r[3] *= inv;
                *(f4v*)(out + qrow * kH + nt * 32 + 8 * g4 + 4 * l5) = r;
            }
        }
        __syncthreads();   // buffer free before next chunk
    }
}

extern "C" void kernel_launch(void* const* d_in, const int* in_sizes, int n_in,
                              void* d_out, int out_size, void* d_ws, size_t ws_size,
                              hipStream_t stream) {
    const float* X  = (const float*)d_in[0];
    const float* Wq = (const float*)d_in[1];
    const float* Wk = (const float*)d_in[2];
    const float* Wv = (const float*)d_in[3];
    unsigned short* ws = (unsigned short*)d_ws;          // q | k | v^T bf16 (25.2 MB)
    unsigned short* Wt = ws + (size_t)3 * kBS * kH;      // +768 KB transposed weights
    float* out = (float*)d_out;

    prep_w<<<dim3(3, 16), 256, 0, stream>>>(Wq, Wk, Wv, Wt);
    qkv_gemm<<<dim3(kBS / 128), 512, 0, stream>>>(X, Wt, ws);
    attn<<<dim3(1024), 256, 0, stream>>>(ws, out);
}

// Round 7
// 291.740 us; speedup vs baseline: 1.0132x; 1.0132x over previous
//
#include <hip/hip_runtime.h>
#include <hip/hip_bf16.h>

#define kB 16
#define kS 2048
#define kD 1024
#define kH 128
#define kBS (kB * kS)

typedef short s8v __attribute__((ext_vector_type(8)));
typedef float f4v __attribute__((ext_vector_type(4)));
typedef float f16v __attribute__((ext_vector_type(16)));
typedef unsigned short us4 __attribute__((ext_vector_type(4)));
typedef unsigned short us8 __attribute__((ext_vector_type(8)));

__device__ __forceinline__ unsigned short f2bf(float f) {
    __hip_bfloat16 h = __float2bfloat16(f);
    return __builtin_bit_cast(unsigned short, h);
}

// async global->LDS DMA, 16B per lane, LDS dest = wave-uniform base + lane*16
__device__ __forceinline__ void gl16(const void* g, void* l) {
    __builtin_amdgcn_global_load_lds(
        (const __attribute__((address_space(1))) unsigned int*)g,
        (__attribute__((address_space(3))) unsigned int*)l, 16, 0, 0);
}

// ---------------------------------------------------------------------------
// Kernel 0: W[1024][128] fp32 -> Wt[384][1024] bf16 (transposed, q|k|v).
// Wq pre-scaled by H^-0.5.  (unchanged)
// ---------------------------------------------------------------------------
__global__ void prep_w(const float* __restrict__ Wq, const float* __restrict__ Wk,
                       const float* __restrict__ Wv, unsigned short* __restrict__ Wt)
{
    const int g = blockIdx.x;
    const float* W = (g == 0) ? Wq : (g == 1) ? Wk : Wv;
    const float sc = (g == 0) ? 0.08838834764831845f : 1.0f;  // 128^-0.5 folded into Wq
    unsigned short* o = Wt + (size_t)g * 128 * 1024;
    const int t = threadIdx.x;
    const int n = t & 127;
    const int half = t >> 7;
    const int kbase = blockIdx.y * 64 + half * 32;
    #pragma unroll
    for (int c = 0; c < 4; ++c) {
        int kb = kbase + c * 8;
        us8 v;
        #pragma unroll
        for (int j = 0; j < 8; ++j) v[j] = f2bf(W[(size_t)(kb + j) * kH + n] * sc);
        *(us8*)(o + (size_t)n * 1024 + kb) = v;
    }
}

// ---------------------------------------------------------------------------
// Kernel 1 (R9, unchanged): fused QKV GEMM, m97-shape. BM=128 x BN=384,
// BK=64, 16 steps. 8 waves (2m x 4n), acc[4][6]. 256 blocks = 1/CU.
// B via global_load_lds with both-sides XOR chunk swizzle; A reg-staged.
// ---------------------------------------------------------------------------
#define AOFF(b_) ((b_) * 8704)
#define BOFF(b_) (17408 + (b_) * 24576)

#define STAGE(b_, tt_) do {                                                   \
    _Pragma("unroll")                                                         \
    for (int u = 0; u < 4; ++u)                                               \
        xa[u] = *(const float4*)(Xp + (tt_) * 64 + u * 4);                    \
    _Pragma("unroll")                                                         \
    for (int ci = 0; ci < 6; ++ci) {                                          \
        const int rb = w * 48 + ci * 8;                                       \
        gl16(WpL + (size_t)rb * 1024 + (tt_) * 64, &smem[BOFF(b_) + rb * 64]);\
    }                                                                         \
} while (0)

#define AWRITE(b_) do {                                                       \
    _Pragma("unroll")                                                         \
    for (int u2 = 0; u2 < 2; ++u2) {                                          \
        us8 aw;                                                               \
        aw[0] = f2bf(xa[2*u2].x);   aw[1] = f2bf(xa[2*u2].y);                 \
        aw[2] = f2bf(xa[2*u2].z);   aw[3] = f2bf(xa[2*u2].w);                 \
        aw[4] = f2bf(xa[2*u2+1].x); aw[5] = f2bf(xa[2*u2+1].y);               \
        aw[6] = f2bf(xa[2*u2+1].z); aw[7] = f2bf(xa[2*u2+1].w);               \
        *(us8*)&smem[AOFF(b_) + arow * 68 + ac16 + u2 * 8] = aw;              \
    }                                                                         \
} while (0)

__global__ __launch_bounds__(512, 2) void qkv_gemm(
    const float* __restrict__ X, const unsigned short* __restrict__ Wt,
    unsigned short* __restrict__ ws)
{
    __shared__ __align__(16) unsigned short smem[66560];   // 133 KB

    const int t    = threadIdx.x;
    const int L    = t & 63;
    const int w    = t >> 6;                 // wave 0..7
    const int wr   = w >> 2;                 // m-half 0..1
    const int wc   = w & 3;                  // n-quarter 0..3
    const int col  = L & 15;
    const int quad = L >> 4;
    const int m0   = blockIdx.x * 128;

    f4v acc[4][6];
    #pragma unroll
    for (int i = 0; i < 4; ++i)
        #pragma unroll
        for (int j = 0; j < 6; ++j) { f4v z = {0.f, 0.f, 0.f, 0.f}; acc[i][j] = z; }

    const int arow = t >> 2;                 // 0..127
    const int ac16 = (t & 3) * 16;           // k-base 0,16,32,48
    const float* Xp = X + (size_t)(m0 + arow) * kD + ac16;
    // B DMA source, pre-swizzled: lane L covers row rb+(L>>3), LDS chunk (L&7)
    // holds global chunk (L&7)^(L>>3)
    const unsigned short* WpL = Wt + (size_t)(L >> 3) * 1024
                                + (((L & 7) ^ (L >> 3)) * 8);

    float4 xa[4];

    STAGE(0, 0);
    AWRITE(0);
    __syncthreads();     // drains tile-0 DMAs

    #pragma unroll 2
    for (int tt = 0; tt < 16; ++tt) {
        const int cb = tt & 1;
        if (tt < 15) STAGE(cb ^ 1, tt + 1);     // fire-and-forget next tile
        const int ab = AOFF(cb), bbs = BOFF(cb);
        #pragma unroll
        for (int ks = 0; ks < 2; ++ks) {
            s8v Af[4], Bf[6];
            #pragma unroll
            for (int i = 0; i < 4; ++i)
                Af[i] = *(const s8v*)&smem[ab + (wr * 64 + i * 16 + col) * 68
                                           + ks * 32 + quad * 8];
            const int swz = (((ks * 4 + quad) ^ (col & 7)) * 8);
            #pragma unroll
            for (int j = 0; j < 6; ++j) {
                const int n = wc * 96 + j * 16 + col;
                Bf[j] = *(const s8v*)&smem[bbs + n * 64 + swz];
            }
            #pragma unroll
            for (int i = 0; i < 4; ++i)
                #pragma unroll
                for (int j = 0; j < 6; ++j)
                    acc[i][j] = __builtin_amdgcn_mfma_f32_16x16x32_bf16(
                        Af[i], Bf[j], acc[i][j], 0, 0, 0);
        }
        if (tt < 15) AWRITE(cb ^ 1);
        __syncthreads();
    }

    // ---- epilogue: repack via LDS, write q/k [s][h] and v^T [b][h][s] ----
    for (int g = 0; g < 3; ++g) {
        __syncthreads();
        #pragma unroll
        for (int j = 0; j < 6; ++j) {
            if (((96 * wc + 16 * j) >> 7) != g) continue;   // wave-uniform
            int n = 96 * wc + 16 * j + col;
            if (g < 2) {
                int ng = n - g * 128;
                #pragma unroll
                for (int i = 0; i < 4; ++i)
                    #pragma unroll
                    for (int rg = 0; rg < 4; ++rg)
                        smem[(wr * 64 + i * 16 + quad * 4 + rg) * 136 + ng] =
                            f2bf(acc[i][j][rg]);
            } else {
                int h = n - 256;
                #pragma unroll
                for (int i = 0; i < 4; ++i) {
                    us4 pk = { f2bf(acc[i][j][0]), f2bf(acc[i][j][1]),
                               f2bf(acc[i][j][2]), f2bf(acc[i][j][3]) };
                    *(us4*)&smem[h * 136 + wr * 64 + i * 16 + quad * 4] = pk;
                }
            }
        }
        __syncthreads();
        if (g < 2) {
            unsigned short* outp = ws + (size_t)g * kBS * kH;
            int row = t >> 2, hc = (t & 3) * 32;
            #pragma unroll
            for (int u = 0; u < 4; ++u) {
                us8 v = *(const us8*)&smem[row * 136 + hc + u * 8];
                *(us8*)(outp + (size_t)(m0 + row) * kH + hc + u * 8) = v;
            }
        } else {
            unsigned short* vtp = ws + (size_t)2 * kBS * kH;
            int h = t >> 2, sc2 = (t & 3) * 32;
            int bb = m0 >> 11, sl = m0 & 2047;
            #pragma unroll
            for (int u = 0; u < 4; ++u) {
                us8 v = *(const us8*)&smem[h * 136 + sc2 + u * 8];
                *(us8*)(vtp + ((size_t)bb * kH + h) * kS + sl + sc2 + u * 8) = v;
            }
        }
    }
}

// ---------------------------------------------------------------------------
// Kernel 2 (R11): causal attention — 4-wave split-K, BALANCED 2D grid
// restored (R10's 1D XCD remap gave 68..192 tiles/CU vs this grid's
// constant 130 -> tail + 16% occupancy). Grid dim3(kB,64): flat order
// b+16y walks slot quadrants by round, per-CU sum (63-i)+(32+i)+(31-i)+i
// +4 = 130; XCD = b&7 -> 2 batches/XCD L2 locality for free.
// Added: QK^T chain split into two 4-deep MFMA chains (latency exposed at
// low occupancy; halves the serial depth, +16 VGPR, stays <=128).
// ---------------------------------------------------------------------------
__global__ __launch_bounds__(256, 2) void attn(
    const unsigned short* __restrict__ ws, float* __restrict__ out)
{
    __shared__ float Ob[4096];               // 16 KB combine chunk
    __shared__ float Lsums[128];
    __shared__ unsigned short Ps[4 * 1152];  // per-wave P[32][36]

    const int t   = threadIdx.x;
    const int w   = t >> 6;                  // wave 0..3
    const int L   = t & 63;
    const int l5  = L >> 5;
    const int c32 = L & 31;
    const int b   = blockIdx.x;
    const int g2  = blockIdx.y >> 4, ii = blockIdx.y & 15;
    const int s   = (g2 == 0) ? 63 - ii : (g2 == 1) ? 32 + ii
                  : (g2 == 2) ? 31 - ii : ii;          // bijective onto 0..63

    const unsigned short* qp = ws;
    const unsigned short* kp = ws + (size_t)kBS * kH + (size_t)b * kS * kH;
    const unsigned short* vt = ws + (size_t)2 * kBS * kH + (size_t)b * kH * kS;

    const size_t qrow = (size_t)b * kS + s * 32 + c32;
    unsigned short* myPs = Ps + w * 1152;

    // Q B-frags (n=lane&31 -> q=c32, k=l5*8+j at k-offset ks*16)
    s8v Qf[8];
    #pragma unroll
    for (int ks = 0; ks < 8; ++ks)
        Qf[ks] = *(const s8v*)(qp + qrow * kH + ks * 16 + l5 * 8);

    f16v O[4];
    #pragma unroll
    for (int nt = 0; nt < 4; ++nt)
        #pragma unroll
        for (int r = 0; r < 16; ++r) O[nt][r] = 0.f;
    float lsum = 0.f;

    // prefetch first K tile of this wave (rows w*32+c32 always in-bounds)
    s8v Kf[8];
    #pragma unroll
    for (int ks = 0; ks < 8; ++ks)
        Kf[ks] = *(const s8v*)(kp + (size_t)(w * 32 + c32) * kH + ks * 16 + l5 * 8);

    for (int T = w; T <= s; T += 4) {
        const int kb = T * 32;
        // V^T A-frags (m = h within 32-group = c32, k = key)
        s8v Vf[2][4];
        #pragma unroll
        for (int k2 = 0; k2 < 2; ++k2)
            #pragma unroll
            for (int nt = 0; nt < 4; ++nt)
                Vf[k2][nt] = *(const s8v*)(vt + (size_t)(nt * 32 + c32) * kS
                                           + kb + k2 * 16 + l5 * 8);
        // S^T = K Q^T — two independent 4-deep chains, then combine
        f16v Sv, Sv1;
        #pragma unroll
        for (int r = 0; r < 16; ++r) { Sv[r] = 0.f; Sv1[r] = 0.f; }
        #pragma unroll
        for (int ks = 0; ks < 4; ++ks) {
            Sv  = __builtin_amdgcn_mfma_f32_32x32x16_bf16(Kf[ks],     Qf[ks],     Sv,  0, 0, 0);
            Sv1 = __builtin_amdgcn_mfma_f32_32x32x16_bf16(Kf[ks + 4], Qf[ks + 4], Sv1, 0, 0, 0);
        }
        Sv = Sv + Sv1;
        // prefetch this wave's next K tile (stride 4 tiles = +128 rows)
        if (T + 4 <= s) {
            #pragma unroll
            for (int ks = 0; ks < 8; ++ks)
                Kf[ks] = *(const s8v*)(kp + (size_t)(kb + 128 + c32) * kH + ks * 16 + l5 * 8);
        }
        // mask (diagonal tile) + exp + P store; lane holds 16 keys of q=c32
        const bool dm = (T == s);
        #pragma unroll
        for (int g4 = 0; g4 < 4; ++g4) {
            us4 pk;
            #pragma unroll
            for (int u = 0; u < 4; ++u) {
                int krow = u + 8 * g4 + 4 * l5;       // C-layout row = key
                float v = Sv[g4 * 4 + u];
                if (dm && krow > c32) v = -__builtin_inff();
                float e = __expf(v);
                lsum += e;
                pk[u] = f2bf(e);
            }
            *(us4*)&myPs[c32 * 36 + 8 * g4 + 4 * l5] = pk;
        }
        // O^T += V^T P^T (same-wave LDS roundtrip)
        #pragma unroll
        for (int k2 = 0; k2 < 2; ++k2) {
            us4 plo = *(const us4*)&myPs[c32 * 36 + k2 * 16 + l5 * 8];
            us4 phi = *(const us4*)&myPs[c32 * 36 + k2 * 16 + l5 * 8 + 4];
            us8 pc;
            pc[0]=plo[0]; pc[1]=plo[1]; pc[2]=plo[2]; pc[3]=plo[3];
            pc[4]=phi[0]; pc[5]=phi[1]; pc[6]=phi[2]; pc[7]=phi[3];
            s8v Pb = __builtin_bit_cast(s8v, pc);
            #pragma unroll
            for (int nt = 0; nt < 4; ++nt)
                O[nt] = __builtin_amdgcn_mfma_f32_32x32x16_bf16(Vf[k2][nt], Pb, O[nt], 0, 0, 0);
        }
    }

    // ---- combine partial l across waves ----
    float lw = lsum + __shfl_xor(lsum, 32);      // per-lane q=c32, this wave
    if (l5 == 0) Lsums[w * 32 + c32] = lw;
    __syncthreads();
    const float inv = 1.0f / (Lsums[c32] + Lsums[32 + c32] +
                              Lsums[64 + c32] + Lsums[96 + c32]);

    // ---- combine partial O across waves, chunked by nt (16 KB buffer) ----
    #pragma unroll
    for (int nt = 0; nt < 4; ++nt) {
        #pragma unroll
        for (int g4 = 0; g4 < 4; ++g4) {
            f4v v = { O[nt][g4 * 4 + 0], O[nt][g4 * 4 + 1],
                      O[nt][g4 * 4 + 2], O[nt][g4 * 4 + 3] };
            *(f4v*)&Ob[((w * 4 + g4) * 64 + L) * 4] = v;     // contiguous/wave
        }
        __syncthreads();
        if (w == nt) {
            #pragma unroll
            for (int g4 = 0; g4 < 4; ++g4) {
                f4v a0 = *(const f4v*)&Ob[((0 * 4 + g4) * 64 + L) * 4];
                f4v a1 = *(const f4v*)&Ob[((1 * 4 + g4) * 64 + L) * 4];
                f4v a2 = *(const f4v*)&Ob[((2 * 4 + g4) * 64 + L) * 4];
                f4v a3 = *(const f4v*)&Ob[((3 * 4 + g4) * 64 + L) * 4];
                f4v r = (a0 + a1) + (a2 + a3);
                r[0] *= inv; r[1] *= inv; r[2] *= inv; r[3] *= inv;
                *(f4v*)(out + qrow * kH + nt * 32 + 8 * g4 + 4 * l5) = r;
            }
        }
        __syncthreads();   // buffer free before next chunk
    }
}

extern "C" void kernel_launch(void* const* d_in, const int* in_sizes, int n_in,
                              void* d_out, int out_size, void* d_ws, size_t ws_size,
                              hipStream_t stream) {
    const float* X  = (const float*)d_in[0];
    const float* Wq = (const float*)d_in[1];
    const float* Wk = (const float*)d_in[2];
    const float* Wv = (const float*)d_in[3];
    unsigned short* ws = (unsigned short*)d_ws;          // q | k | v^T bf16 (25.2 MB)
    unsigned short* Wt = ws + (size_t)3 * kBS * kH;      // +768 KB transposed weights
    float* out = (float*)d_out;

    prep_w<<<dim3(3, 16), 256, 0, stream>>>(Wq, Wk, Wv, Wt);
    qkv_gemm<<<dim3(kBS / 128), 512, 0, stream>>>(X, Wt, ws);
    attn<<<dim3(kB, 64), 256, 0, stream>>>(ws, out);
}

// Round 11
// 244.481 us; speedup vs baseline: 1.2091x; 1.1933x over previous
//
#include <hip/hip_runtime.h>
#include <hip/hip_bf16.h>

#define kB 16
#define kS 2048
#define kD 1024
#define kH 128
#define kBS (kB * kS)

typedef short s8v __attribute__((ext_vector_type(8)));
typedef float f4v __attribute__((ext_vector_type(4)));
typedef float f16v __attribute__((ext_vector_type(16)));
typedef unsigned short us4 __attribute__((ext_vector_type(4)));
typedef unsigned short us8 __attribute__((ext_vector_type(8)));

__device__ __forceinline__ unsigned short f2bf(float f) {
    __hip_bfloat16 h = __float2bfloat16(f);
    return __builtin_bit_cast(unsigned short, h);
}

// async global->LDS DMA, 16B per lane, LDS dest = wave-uniform base + lane*16
__device__ __forceinline__ void gl16(const void* g, void* l) {
    __builtin_amdgcn_global_load_lds(
        (const __attribute__((address_space(1))) unsigned int*)g,
        (__attribute__((address_space(3))) unsigned int*)l, 16, 0, 0);
}

// ---------------------------------------------------------------------------
// ws layout (R13): FRAGMENT-ORDER tensors, 4096 shorts (8 KB) per 32-row tile:
//   Q' [b][slot 0..63][ks 0..7][lane 0..63][8]   q[b][slot*32+(L&31)][ks*16+(L>>5)*8..]
//   K' [b][tile 0..63][ks 0..7][lane 0..63][8]   k[b][tile*32+(L&31)][ks*16+(L>>5)*8..]
//   V' [b][tile 0..63][k2 0..1][nt 0..3][lane][8] v^T[b][nt*32+(L&31)][tile*32+k2*16+(L>>5)*8..]
// Every attn load = 64 lanes x consecutive 16B = one 1 KB coalesced transaction.
// ---------------------------------------------------------------------------

// ---------------------------------------------------------------------------
// Kernel 0: W[1024][128] fp32 -> Wt[384][1024] bf16 (transposed, q|k|v).
// Wq pre-scaled by H^-0.5.  (unchanged)
// ---------------------------------------------------------------------------
__global__ void prep_w(const float* __restrict__ Wq, const float* __restrict__ Wk,
                       const float* __restrict__ Wv, unsigned short* __restrict__ Wt)
{
    const int g = blockIdx.x;
    const float* W = (g == 0) ? Wq : (g == 1) ? Wk : Wv;
    const float sc = (g == 0) ? 0.08838834764831845f : 1.0f;  // 128^-0.5 folded into Wq
    unsigned short* o = Wt + (size_t)g * 128 * 1024;
    const int t = threadIdx.x;
    const int n = t & 127;
    const int half = t >> 7;
    const int kbase = blockIdx.y * 64 + half * 32;
    #pragma unroll
    for (int c = 0; c < 4; ++c) {
        int kb = kbase + c * 8;
        us8 v;
        #pragma unroll
        for (int j = 0; j < 8; ++j) v[j] = f2bf(W[(size_t)(kb + j) * kH + n] * sc);
        *(us8*)(o + (size_t)n * 1024 + kb) = v;
    }
}

// ---------------------------------------------------------------------------
// Kernel 1 (R13): fused QKV GEMM, m97-shape (main loop unchanged from R9).
// Epilogue stores Q'/K'/V' in fragment order. R12 bug fixed: repack loop is
// 4 x 512 threads = exactly 2048 fragment slots (was 8 x 256 with 512
// threads -> tl=4 out-of-range cross-block garbage writes -> NaN).
// ---------------------------------------------------------------------------
#define AOFF(b_) ((b_) * 8704)
#define BOFF(b_) (17408 + (b_) * 24576)

#define STAGE(b_, tt_) do {                                                   \
    _Pragma("unroll")                                                         \
    for (int u = 0; u < 4; ++u)                                               \
        xa[u] = *(const float4*)(Xp + (tt_) * 64 + u * 4);                    \
    _Pragma("unroll")                                                         \
    for (int ci = 0; ci < 6; ++ci) {                                          \
        const int rb = w * 48 + ci * 8;                                       \
        gl16(WpL + (size_t)rb * 1024 + (tt_) * 64, &smem[BOFF(b_) + rb * 64]);\
    }                                                                         \
} while (0)

#define AWRITE(b_) do {                                                       \
    _Pragma("unroll")                                                         \
    for (int u2 = 0; u2 < 2; ++u2) {                                          \
        us8 aw;                                                               \
        aw[0] = f2bf(xa[2*u2].x);   aw[1] = f2bf(xa[2*u2].y);                 \
        aw[2] = f2bf(xa[2*u2].z);   aw[3] = f2bf(xa[2*u2].w);                 \
        aw[4] = f2bf(xa[2*u2+1].x); aw[5] = f2bf(xa[2*u2+1].y);               \
        aw[6] = f2bf(xa[2*u2+1].z); aw[7] = f2bf(xa[2*u2+1].w);               \
        *(us8*)&smem[AOFF(b_) + arow * 68 + ac16 + u2 * 8] = aw;              \
    }                                                                         \
} while (0)

__global__ __launch_bounds__(512, 2) void qkv_gemm(
    const float* __restrict__ X, const unsigned short* __restrict__ Wt,
    unsigned short* __restrict__ ws)
{
    __shared__ __align__(16) unsigned short smem[66560];   // 133 KB

    const int t    = threadIdx.x;
    const int L    = t & 63;
    const int w    = t >> 6;                 // wave 0..7
    const int wr   = w >> 2;                 // m-half 0..1
    const int wc   = w & 3;                  // n-quarter 0..3
    const int col  = L & 15;
    const int quad = L >> 4;
    const int m0   = blockIdx.x * 128;

    f4v acc[4][6];
    #pragma unroll
    for (int i = 0; i < 4; ++i)
        #pragma unroll
        for (int j = 0; j < 6; ++j) { f4v z = {0.f, 0.f, 0.f, 0.f}; acc[i][j] = z; }

    const int arow = t >> 2;                 // 0..127
    const int ac16 = (t & 3) * 16;           // k-base 0,16,32,48
    const float* Xp = X + (size_t)(m0 + arow) * kD + ac16;
    // B DMA source, pre-swizzled: lane L covers row rb+(L>>3), LDS chunk (L&7)
    // holds global chunk (L&7)^(L>>3)
    const unsigned short* WpL = Wt + (size_t)(L >> 3) * 1024
                                + (((L & 7) ^ (L >> 3)) * 8);

    float4 xa[4];

    STAGE(0, 0);
    AWRITE(0);
    __syncthreads();     // drains tile-0 DMAs

    #pragma unroll 2
    for (int tt = 0; tt < 16; ++tt) {
        const int cb = tt & 1;
        if (tt < 15) STAGE(cb ^ 1, tt + 1);     // fire-and-forget next tile
        const int ab = AOFF(cb), bbs = BOFF(cb);
        #pragma unroll
        for (int ks = 0; ks < 2; ++ks) {
            s8v Af[4], Bf[6];
            #pragma unroll
            for (int i = 0; i < 4; ++i)
                Af[i] = *(const s8v*)&smem[ab + (wr * 64 + i * 16 + col) * 68
                                           + ks * 32 + quad * 8];
            const int swz = (((ks * 4 + quad) ^ (col & 7)) * 8);
            #pragma unroll
            for (int j = 0; j < 6; ++j) {
                const int n = wc * 96 + j * 16 + col;
                Bf[j] = *(const s8v*)&smem[bbs + n * 64 + swz];
            }
            #pragma unroll
            for (int i = 0; i < 4; ++i)
                #pragma unroll
                for (int j = 0; j < 6; ++j)
                    acc[i][j] = __builtin_amdgcn_mfma_f32_16x16x32_bf16(
                        Af[i], Bf[j], acc[i][j], 0, 0, 0);
        }
        if (tt < 15) AWRITE(cb ^ 1);
        __syncthreads();
    }

    // ---- epilogue: repack via LDS, store in FRAGMENT order ----
    const int bb = m0 >> 11, sl = m0 & 2047;
    const size_t tbase = ((size_t)bb * 64 + (sl >> 5));   // first 32-row tile

    for (int g = 0; g < 3; ++g) {
        __syncthreads();
        #pragma unroll
        for (int j = 0; j < 6; ++j) {
            if (((96 * wc + 16 * j) >> 7) != g) continue;   // wave-uniform
            int n = 96 * wc + 16 * j + col;
            if (g < 2) {
                int ng = n - g * 128;
                #pragma unroll
                for (int i = 0; i < 4; ++i)
                    #pragma unroll
                    for (int rg = 0; rg < 4; ++rg)
                        smem[(wr * 64 + i * 16 + quad * 4 + rg) * 136 + ng] =
                            f2bf(acc[i][j][rg]);
            } else {
                int h = n - 256;
                #pragma unroll
                for (int i = 0; i < 4; ++i) {
                    us4 pk = { f2bf(acc[i][j][0]), f2bf(acc[i][j][1]),
                               f2bf(acc[i][j][2]), f2bf(acc[i][j][3]) };
                    *(us4*)&smem[h * 136 + wr * 64 + i * 16 + quad * 4] = pk;
                }
            }
        }
        __syncthreads();
        if (g < 2) {
            // smem = C[s_local 0..127][h 0..127]; emit Q'/K' fragment order
            unsigned short* outp = ws + (size_t)g * kBS * kH + tbase * 4096;
            #pragma unroll
            for (int u = 0; u < 4; ++u) {
                int C  = u * 512 + t;                     // 0..2047, exact
                int Lp = C & 63, ksp = (C >> 6) & 7, tl = C >> 9;   // tl 0..3
                us8 v = *(const us8*)&smem[(tl * 32 + (Lp & 31)) * 136
                                           + ksp * 16 + (Lp >> 5) * 8];
                *(us8*)(outp + ((size_t)tl * 8 + ksp) * 512 + Lp * 8) = v;
            }
        } else {
            // smem = V^T[h 0..127][s_local 0..127]; emit V' fragment order
            unsigned short* vtp = ws + (size_t)2 * kBS * kH + tbase * 4096;
            #pragma unroll
            for (int u = 0; u < 4; ++u) {
                int C   = u * 512 + t;                    // 0..2047, exact
                int Lp  = C & 63, ntp = (C >> 6) & 3, k2p = (C >> 8) & 1, tl = C >> 9;
                us8 v = *(const us8*)&smem[(ntp * 32 + (Lp & 31)) * 136
                                           + tl * 32 + k2p * 16 + (Lp >> 5) * 8];
                *(us8*)(vtp + (((size_t)tl * 2 + k2p) * 4 + ntp) * 512 + Lp * 8) = v;
            }
        }
    }
}

// ---------------------------------------------------------------------------
// Kernel 2 (R13): causal attention — 4-wave split-K, balanced 2D grid
// (unchanged math from R11). All global loads hit the fragment-order
// tensors: 64 lanes x consecutive 16B = 1 KB coalesced per instruction
// (was a 32-line scatter per instruction -> TA request-bound).
// ---------------------------------------------------------------------------
__global__ __launch_bounds__(256, 2) void attn(
    const unsigned short* __restrict__ ws, float* __restrict__ out)
{
    __shared__ float Ob[4096];               // 16 KB combine chunk
    __shared__ float Lsums[128];
    __shared__ unsigned short Ps[4 * 1152];  // per-wave P[32][36]

    const int t   = threadIdx.x;
    const int w   = t >> 6;                  // wave 0..3
    const int L   = t & 63;
    const int l5  = L >> 5;
    const int c32 = L & 31;
    const int b   = blockIdx.x;
    const int g2  = blockIdx.y >> 4, ii = blockIdx.y & 15;
    const int s   = (g2 == 0) ? 63 - ii : (g2 == 1) ? 32 + ii
                  : (g2 == 2) ? 31 - ii : ii;          // bijective onto 0..63

    // fragment-order bases (each already offset by this lane's 16B slot)
    const unsigned short* qp2 = ws + ((size_t)b * 64 + s) * 4096 + L * 8;
    const unsigned short* kp2 = ws + (size_t)kBS * kH + (size_t)b * kS * kH + L * 8;
    const unsigned short* vp2 = ws + (size_t)2 * kBS * kH + (size_t)b * kS * kH + L * 8;

    const size_t qrow = (size_t)b * kS + s * 32 + c32;   // for output only
    unsigned short* myPs = Ps + w * 1152;

    // Q B-frags: one 1 KB coalesced load per ks
    s8v Qf[8];
    #pragma unroll
    for (int ks = 0; ks < 8; ++ks)
        Qf[ks] = *(const s8v*)(qp2 + ks * 512);

    f16v O[4];
    #pragma unroll
    for (int nt = 0; nt < 4; ++nt)
        #pragma unroll
        for (int r = 0; r < 16; ++r) O[nt][r] = 0.f;
    float lsum = 0.f;

    // prefetch first K tile of this wave
    s8v Kf[8];
    #pragma unroll
    for (int ks = 0; ks < 8; ++ks)
        Kf[ks] = *(const s8v*)(kp2 + (size_t)w * 4096 + ks * 512);

    for (int T = w; T <= s; T += 4) {
        // V^T A-frags: 8 coalesced 1 KB loads
        const unsigned short* vpT = vp2 + (size_t)T * 4096;
        s8v Vf[2][4];
        #pragma unroll
        for (int k2 = 0; k2 < 2; ++k2)
            #pragma unroll
            for (int nt = 0; nt < 4; ++nt)
                Vf[k2][nt] = *(const s8v*)(vpT + (k2 * 4 + nt) * 512);
        // S^T = K Q^T — two independent 4-deep chains, then combine
        f16v Sv, Sv1;
        #pragma unroll
        for (int r = 0; r < 16; ++r) { Sv[r] = 0.f; Sv1[r] = 0.f; }
        #pragma unroll
        for (int ks = 0; ks < 4; ++ks) {
            Sv  = __builtin_amdgcn_mfma_f32_32x32x16_bf16(Kf[ks],     Qf[ks],     Sv,  0, 0, 0);
            Sv1 = __builtin_amdgcn_mfma_f32_32x32x16_bf16(Kf[ks + 4], Qf[ks + 4], Sv1, 0, 0, 0);
        }
        Sv = Sv + Sv1;
        // prefetch this wave's next K tile (stride 4 tiles)
        if (T + 4 <= s) {
            const unsigned short* kpT = kp2 + (size_t)(T + 4) * 4096;
            #pragma unroll
            for (int ks = 0; ks < 8; ++ks)
                Kf[ks] = *(const s8v*)(kpT + ks * 512);
        }
        // mask (diagonal tile) + exp + P store; lane holds 16 keys of q=c32
        const bool dm = (T == s);
        #pragma unroll
        for (int g4 = 0; g4 < 4; ++g4) {
            us4 pk;
            #pragma unroll
            for (int u = 0; u < 4; ++u) {
                int krow = u + 8 * g4 + 4 * l5;       // C-layout row = key
                float v = Sv[g4 * 4 + u];
                if (dm && krow > c32) v = -__builtin_inff();
                float e = __expf(v);
                lsum += e;
                pk[u] = f2bf(e);
            }
            *(us4*)&myPs[c32 * 36 + 8 * g4 + 4 * l5] = pk;
        }
        // O^T += V^T P^T (same-wave LDS roundtrip)
        #pragma unroll
        for (int k2 = 0; k2 < 2; ++k2) {
            us4 plo = *(const us4*)&myPs[c32 * 36 + k2 * 16 + l5 * 8];
            us4 phi = *(const us4*)&myPs[c32 * 36 + k2 * 16 + l5 * 8 + 4];
            us8 pc;
            pc[0]=plo[0]; pc[1]=plo[1]; pc[2]=plo[2]; pc[3]=plo[3];
            pc[4]=phi[0]; pc[5]=phi[1]; pc[6]=phi[2]; pc[7]=phi[3];
            s8v Pb = __builtin_bit_cast(s8v, pc);
            #pragma unroll
            for (int nt = 0; nt < 4; ++nt)
                O[nt] = __builtin_amdgcn_mfma_f32_32x32x16_bf16(Vf[k2][nt], Pb, O[nt], 0, 0, 0);
        }
    }

    // ---- combine partial l across waves ----
    float lw = lsum + __shfl_xor(lsum, 32);      // per-lane q=c32, this wave
    if (l5 == 0) Lsums[w * 32 + c32] = lw;
    __syncthreads();
    const float inv = 1.0f / (Lsums[c32] + Lsums[32 + c32] +
                              Lsums[64 + c32] + Lsums[96 + c32]);

    // ---- combine partial O across waves, chunked by nt (16 KB buffer) ----
    #pragma unroll
    for (int nt = 0; nt < 4; ++nt) {
        #pragma unroll
        for (int g4 = 0; g4 < 4; ++g4) {
            f4v v = { O[nt][g4 * 4 + 0], O[nt][g4 * 4 + 1],
                      O[nt][g4 * 4 + 2], O[nt][g4 * 4 + 3] };
            *(f4v*)&Ob[((w * 4 + g4) * 64 + L) * 4] = v;     // contiguous/wave
        }
        __syncthreads();
        if (w == nt) {
            #pragma unroll
            for (int g4 = 0; g4 < 4; ++g4) {
                f4v a0 = *(const f4v*)&Ob[((0 * 4 + g4) * 64 + L) * 4];
                f4v a1 = *(const f4v*)&Ob[((1 * 4 + g4) * 64 + L) * 4];
                f4v a2 = *(const f4v*)&Ob[((2 * 4 + g4) * 64 + L) * 4];
                f4v a3 = *(const f4v*)&Ob[((3 * 4 + g4) * 64 + L) * 4];
                f4v r = (a0 + a1) + (a2 + a3);
                r[0] *= inv; r[1] *= inv; r[2] *= inv; r[3] *= inv;
                *(f4v*)(out + qrow * kH + nt * 32 + 8 * g4 + 4 * l5) = r;
            }
        }
        __syncthreads();   // buffer free before next chunk
    }
}

extern "C" void kernel_launch(void* const* d_in, const int* in_sizes, int n_in,
                              void* d_out, int out_size, void* d_ws, size_t ws_size,
                              hipStream_t stream) {
    const float* X  = (const float*)d_in[0];
    const float* Wq = (const float*)d_in[1];
    const float* Wk = (const float*)d_in[2];
    const float* Wv = (const float*)d_in[3];
    unsigned short* ws = (unsigned short*)d_ws;          // Q' | K' | V' bf16 (25.2 MB)
    unsigned short* Wt = ws + (size_t)3 * kBS * kH;      // +768 KB transposed weights
    float* out = (float*)d_out;

    prep_w<<<dim3(3, 16), 256, 0, stream>>>(Wq, Wk, Wv, Wt);
    qkv_gemm<<<dim3(kBS / 128), 512, 0, stream>>>(X, Wt, ws);
    attn<<<dim3(kB, 64), 256, 0, stream>>>(ws, out);
}